// Round 6
// baseline (552.521 us; speedup 1.0000x reference)
//
#include <hip/hip_runtime.h>
#include <hip/hip_cooperative_groups.h>
#include <math.h>

namespace cg = cooperative_groups;

namespace {
constexpr float LN_EPS = 1e-5f;

typedef unsigned short u16;
typedef __attribute__((ext_vector_type(8))) short bh8;
typedef __attribute__((ext_vector_type(4))) float fv4;

__device__ __forceinline__ float4 ld4(const float* p) { return *reinterpret_cast<const float4*>(p); }

__device__ __forceinline__ float b2f(u16 x) {
  union { float f; unsigned u; } c; c.u = ((unsigned)x) << 16; return c.f;
}
__device__ __forceinline__ u16 f2b(float f) {  // RTN-even
  union { float f; unsigned u; } c; c.f = f;
  unsigned u = c.u;
  u += 0x7FFFu + ((u >> 16) & 1u);
  return (u16)(u >> 16);
}
__device__ __forceinline__ unsigned pk2(float a, float b) {
  return (unsigned)f2b(a) | ((unsigned)f2b(b) << 16);
}
__device__ __forceinline__ uint4 pack8(const float* v) {
  uint4 r; r.x = pk2(v[0], v[1]); r.y = pk2(v[2], v[3]); r.z = pk2(v[4], v[5]); r.w = pk2(v[6], v[7]);
  return r;
}

// XOR-swizzled LDS tile access: [64][64] u16, 16B slots, c8 ^= row&7
__device__ __forceinline__ bh8 lds_rd(const u16* S, int row, int c8) {
  return *(const bh8*)&S[row * 64 + ((c8 ^ (row & 7)) << 3)];
}

// ===========================================================================
// Mega-arg struct: every pointer both paths need
// ===========================================================================
struct FA {
  const float *q, *k, *Wq, *Wk, *Wv, *Wfc, *Wg, *bg, *Wvp, *bvp;
  const float *ln1g, *ln1b, *ln2g, *ln2b;
  float* out;
  u16 *q_bf, *Wg_bf, *Wq_bf, *Wvp_bf, *WkT_bf, *Wv_bf, *Wfc_bf, *k_bf, *kT_bf, *qh_bf;
  float *gam, *bet, *condpre;
  u16 *cb_bf, *cbT_bf, *u_bf, *w1_bf;
  float *c2, *c3, *c4;
  u16* A96_bf;
  float *sum_be, *sum_be2, *P;
  u16* s_bf;
  float* logits;
  u16 *cbsq_bf, *w_bf, *W1_bf;
  float *S1, *S2;
  u16* attn_bf;
};

// ===========================================================================
// GEMM cores (verified rounds 4-5, unchanged numerics)
// ===========================================================================
struct GA {
  const u16* A; const u16* B; const u16* Balt;
  long lda, ldb, sAz, sBz;
  float* Cf; u16* Cb; float* Cf2;
  long ldc, sCz;
  int M, K, epi;
  const float* e0;
};

__device__ __forceinline__ void gemm_core(const GA& a, u16* As, u16* Bs,
                                          int bx, int by, int bz, int t) {
  const int z = bz;
  const int bm0 = bx * 64, bn0 = by * 64;
  const int lane = t & 63, w = t >> 6;
  const int wm = (w >> 1) * 32, wn = (w & 1) * 32;
  const u16* Ab = a.A + (long)z * a.sAz;
  const u16* Bbase = (a.Balt != nullptr && bm0 >= 64) ? a.Balt : a.B;
  const u16* Bb = Bbase + (long)z * a.sBz;

  const int sr = t >> 3, sc8 = t & 7, sc = sc8 * 8;
  int ar0 = bm0 + sr;      if (ar0 > a.M - 1) ar0 = a.M - 1;
  int ar1 = bm0 + sr + 32; if (ar1 > a.M - 1) ar1 = a.M - 1;
  const u16* ap0 = Ab + (long)ar0 * a.lda + sc;
  const u16* ap1 = Ab + (long)ar1 * a.lda + sc;
  const u16* bp0 = Bb + (long)(bn0 + sr) * a.ldb + sc;
  const u16* bp1 = Bb + (long)(bn0 + sr + 32) * a.ldb + sc;
  const int iA0 = sr * 64 + ((sc8 ^ (sr & 7)) << 3);
  const int iA1 = iA0 + 32 * 64;

  fv4 zero = {0.f, 0.f, 0.f, 0.f};
  fv4 acc00 = zero, acc01 = zero, acc10 = zero, acc11 = zero;
  const int r0 = lane & 15, kq8 = lane >> 4;
  const int nk = a.K >> 6;

  uint4 av0 = *(const uint4*)ap0, av1 = *(const uint4*)ap1;
  uint4 bv0 = *(const uint4*)bp0, bv1 = *(const uint4*)bp1;
  for (int kt = 0; kt < nk; ++kt) {
    __syncthreads();
    *(uint4*)&As[iA0] = av0; *(uint4*)&As[iA1] = av1;
    *(uint4*)&Bs[iA0] = bv0; *(uint4*)&Bs[iA1] = bv1;
    __syncthreads();
    if (kt + 1 < nk) {
      ap0 += 64; ap1 += 64; bp0 += 64; bp1 += 64;
      av0 = *(const uint4*)ap0; av1 = *(const uint4*)ap1;
      bv0 = *(const uint4*)bp0; bv1 = *(const uint4*)bp1;
    }
#pragma unroll
    for (int kc = 0; kc < 2; ++kc) {
      const int c8 = kq8 + 4 * kc;
      bh8 aa0 = lds_rd(As, wm + r0, c8);
      bh8 aa1 = lds_rd(As, wm + 16 + r0, c8);
      bh8 bb0 = lds_rd(Bs, wn + r0, c8);
      bh8 bb1 = lds_rd(Bs, wn + 16 + r0, c8);
      acc00 = __builtin_amdgcn_mfma_f32_16x16x32_bf16(aa0, bb0, acc00, 0, 0, 0);
      acc01 = __builtin_amdgcn_mfma_f32_16x16x32_bf16(aa0, bb1, acc01, 0, 0, 0);
      acc10 = __builtin_amdgcn_mfma_f32_16x16x32_bf16(aa1, bb0, acc10, 0, 0, 0);
      acc11 = __builtin_amdgcn_mfma_f32_16x16x32_bf16(aa1, bb1, acc11, 0, 0, 0);
    }
  }

  fv4 accs[2][2] = {{acc00, acc01}, {acc10, acc11}};
#pragma unroll
  for (int rb = 0; rb < 2; ++rb) {
#pragma unroll
    for (int cbl = 0; cbl < 2; ++cbl) {
#pragma unroll
      for (int j = 0; j < 4; ++j) {
        const int r = bm0 + wm + rb * 16 + (lane >> 4) * 4 + j;
        const int c = bn0 + wn + cbl * 16 + (lane & 15);
        if (r >= a.M) continue;
        const float v = accs[rb][cbl][j];
        if (a.epi == 0) {
          a.Cf[(long)z * a.sCz + (long)r * a.ldc + c] = v;
        } else if (a.epi == 1) {
          a.Cb[(long)z * a.sCz + (long)r * a.ldc + c] = f2b(v);
        } else if (a.epi == 2) {  // film
          const float x = tanhf(v + a.e0[c]);
          if (c < 512) a.Cf[(long)r * 512 + c] = x;
          else         a.Cf2[(long)r * 512 + (c - 512)] = x;
        } else if (a.epi == 4) {  // + bias, f32
          a.Cf[(long)r * a.ldc + c] = v + a.e0[c];
        } else {  // 5: u remap, *0.125
          a.Cb[((long)r * 8 + z) * a.ldc + c] = f2b(v * 0.125f);
        }
      }
    }
  }
}

struct GA2 {
  const u16* A1; const u16* A2; const u16* B1; const u16* B2;
  long lda, ldb, sAz, sBz;
  float* Cf; u16* Cb;
  long ldc, sCz;
  int M, K;
  const float* e1; const float* e2; const float* e3;
  const float* e4; const float* e5; const float* e6;
};

__device__ __forceinline__ void gemm2_core(const GA2& a, u16* As1, u16* As2,
                                           u16* Bs1, u16* Bs2,
                                           int bx, int by, int bz, int t, int EPI) {
  const int z = bz;
  const int bm0 = bx * 64, bn0 = by * 64;
  const int lane = t & 63, w = t >> 6;
  const int wm = (w >> 1) * 32, wn = (w & 1) * 32;
  const u16* A1b = a.A1 + (long)z * a.sAz;
  const u16* A2b = a.A2 + (long)z * a.sAz;
  const u16* B1b = a.B1 + (long)z * a.sBz;
  const u16* B2b = a.B2 + (long)z * a.sBz;

  const int sr = t >> 3, sc8 = t & 7, sc = sc8 * 8;
  const long aoff0 = (long)(bm0 + sr) * a.lda + sc;
  const long aoff1 = (long)(bm0 + sr + 32) * a.lda + sc;
  const long boff0 = (long)(bn0 + sr) * a.ldb + sc;
  const long boff1 = (long)(bn0 + sr + 32) * a.ldb + sc;
  const u16 *a1p0 = A1b + aoff0, *a1p1 = A1b + aoff1;
  const u16 *a2p0 = A2b + aoff0, *a2p1 = A2b + aoff1;
  const u16 *b1p0 = B1b + boff0, *b1p1 = B1b + boff1;
  const u16 *b2p0 = B2b + boff0, *b2p1 = B2b + boff1;
  const int iA0 = sr * 64 + ((sc8 ^ (sr & 7)) << 3);
  const int iA1 = iA0 + 32 * 64;

  fv4 zero = {0.f, 0.f, 0.f, 0.f};
  fv4 p00 = zero, p01 = zero, p10 = zero, p11 = zero;
  fv4 q00 = zero, q01 = zero, q10 = zero, q11 = zero;
  const int r0 = lane & 15, kq8 = lane >> 4;
  const int nk = a.K >> 6;

  uint4 a1v0 = *(const uint4*)a1p0, a1v1 = *(const uint4*)a1p1;
  uint4 a2v0 = *(const uint4*)a2p0, a2v1 = *(const uint4*)a2p1;
  uint4 b1v0 = *(const uint4*)b1p0, b1v1 = *(const uint4*)b1p1;
  uint4 b2v0 = *(const uint4*)b2p0, b2v1 = *(const uint4*)b2p1;
  for (int kt = 0; kt < nk; ++kt) {
    __syncthreads();
    *(uint4*)&As1[iA0] = a1v0; *(uint4*)&As1[iA1] = a1v1;
    *(uint4*)&As2[iA0] = a2v0; *(uint4*)&As2[iA1] = a2v1;
    *(uint4*)&Bs1[iA0] = b1v0; *(uint4*)&Bs1[iA1] = b1v1;
    *(uint4*)&Bs2[iA0] = b2v0; *(uint4*)&Bs2[iA1] = b2v1;
    __syncthreads();
    if (kt + 1 < nk) {
      a1p0 += 64; a1p1 += 64; a2p0 += 64; a2p1 += 64;
      b1p0 += 64; b1p1 += 64; b2p0 += 64; b2p1 += 64;
      a1v0 = *(const uint4*)a1p0; a1v1 = *(const uint4*)a1p1;
      a2v0 = *(const uint4*)a2p0; a2v1 = *(const uint4*)a2p1;
      b1v0 = *(const uint4*)b1p0; b1v1 = *(const uint4*)b1p1;
      b2v0 = *(const uint4*)b2p0; b2v1 = *(const uint4*)b2p1;
    }
#pragma unroll
    for (int kc = 0; kc < 2; ++kc) {
      const int c8 = kq8 + 4 * kc;
      bh8 x0 = lds_rd(As1, wm + r0, c8);
      bh8 x1 = lds_rd(As1, wm + 16 + r0, c8);
      bh8 y0 = lds_rd(Bs1, wn + r0, c8);
      bh8 y1 = lds_rd(Bs1, wn + 16 + r0, c8);
      p00 = __builtin_amdgcn_mfma_f32_16x16x32_bf16(x0, y0, p00, 0, 0, 0);
      p01 = __builtin_amdgcn_mfma_f32_16x16x32_bf16(x0, y1, p01, 0, 0, 0);
      p10 = __builtin_amdgcn_mfma_f32_16x16x32_bf16(x1, y0, p10, 0, 0, 0);
      p11 = __builtin_amdgcn_mfma_f32_16x16x32_bf16(x1, y1, p11, 0, 0, 0);
      bh8 u0 = lds_rd(As2, wm + r0, c8);
      bh8 u1 = lds_rd(As2, wm + 16 + r0, c8);
      bh8 v0 = lds_rd(Bs2, wn + r0, c8);
      bh8 v1 = lds_rd(Bs2, wn + 16 + r0, c8);
      q00 = __builtin_amdgcn_mfma_f32_16x16x32_bf16(u0, v0, q00, 0, 0, 0);
      q01 = __builtin_amdgcn_mfma_f32_16x16x32_bf16(u0, v1, q01, 0, 0, 0);
      q10 = __builtin_amdgcn_mfma_f32_16x16x32_bf16(u1, v0, q10, 0, 0, 0);
      q11 = __builtin_amdgcn_mfma_f32_16x16x32_bf16(u1, v1, q11, 0, 0, 0);
    }
  }

  fv4 pa[2][2] = {{p00, p01}, {p10, p11}};
  fv4 qa[2][2] = {{q00, q01}, {q10, q11}};
#pragma unroll
  for (int rb = 0; rb < 2; ++rb) {
#pragma unroll
    for (int cbl = 0; cbl < 2; ++cbl) {
#pragma unroll
      for (int j = 0; j < 4; ++j) {
        const int r = bm0 + wm + rb * 16 + (lane >> 4) * 4 + j;
        const int c = bn0 + wn + cbl * 16 + (lane & 15);
        if (r >= a.M) continue;
        const float v1 = pa[rb][cbl][j];
        const float v2 = qa[rb][cbl][j];
        if (EPI == 0) {  // logits: v1=K1, v2=K2
          const int l = r >> 3;
          const int lh = z * 256 + r;
          const int bl = z * 32 + l;
          const float* Pb = a.e1 + ((long)z * 96 + l) * 256 + c;
          const float P0 = Pb[0], Pgb = Pb[32 * 256], Pg2 = Pb[64 * 256];
          const float mu = (P0 + a.e2[bl]) * (1.f / 512.f);
          const float msq = (Pg2 + 2.f * Pgb + a.e3[bl]) * (1.f / 512.f);
          const float iv = rsqrtf(msq - mu * mu + LN_EPS);
          const float lg = v1 + a.e6[lh] + iv * (v2 + a.e4[lh] - mu * a.e5[lh]);
          a.Cf[(long)z * a.sCz + (long)r * a.ldc + c] = lg;
        } else {  // s: v1=T1, v2=T2
          const int lh = z * 256 + r;
          const int bl = z * 32 + (r >> 3);
          const float G2d = a.e1[c], B2d = a.e2[c];
          const float gv = a.e3[(long)bl * 512 + c];
          const float bev = a.e4[(long)bl * 512 + c];
          const float sv = v1 + B2d + G2d * (gv * v2 + bev * a.e5[lh] - a.e6[lh]);
          a.Cb[(long)z * a.sCz + (long)r * a.ldc + c] = f2b(sv);
        }
      }
    }
  }
}

// ===========================================================================
// Elementwise / transpose unit helpers (verified code, re-wrapped)
// ===========================================================================
__device__ __forceinline__ void tpf32_unit(const float* src, long lds, u16* dst, long ldd,
                                           int tr, int tc, int t, float T[64][65]) {
  __syncthreads();  // protect LDS reuse across units
  const int c = t & 63, rg = t >> 6;
#pragma unroll 4
  for (int i = 0; i < 16; ++i) {
    const int r = rg + 4 * i;
    T[r][c] = src[(long)(tr * 64 + r) * lds + tc * 64 + c];
  }
  __syncthreads();
#pragma unroll 4
  for (int i = 0; i < 16; ++i) {
    const int r = rg + 4 * i;
    dst[(long)(tc * 64 + r) * ldd + tr * 64 + c] = f2b(T[c][r]);
  }
}

__device__ __forceinline__ void tpb16_unit(const u16* src, u16* dst, int b, int w32,
                                           int t, float T[64][65]) {
  __syncthreads();
  const int tr = w32 >> 3, tc = w32 & 7;
  const u16* s = src + (long)b * 131072;
  u16* d = dst + (long)b * 131072;
  const int c = t & 63, rg = t >> 6;
#pragma unroll 4
  for (int i = 0; i < 16; ++i) {
    const int r = rg + 4 * i;
    T[r][c] = b2f(s[(long)(tr * 64 + r) * 512 + tc * 64 + c]);
  }
  __syncthreads();
#pragma unroll 4
  for (int i = 0; i < 16; ++i) {
    const int r = rg + 4 * i;
    d[(long)(tc * 64 + r) * 256 + tr * 64 + c] = f2b(T[c][r]);
  }
}

__device__ __forceinline__ void ln_unit(const FA& f, int u, int t) {
  const int lane = t & 63, e = lane * 8;
  const int row = u * 4 + (t >> 6);
  const float* p = f.condpre + (long)row * 512 + e;
  const float4 x0 = ld4(p), x1 = ld4(p + 4);
  float v[8] = {x0.x, x0.y, x0.z, x0.w, x1.x, x1.y, x1.z, x1.w};
  float s = 0.f, sq = 0.f;
#pragma unroll
  for (int i = 0; i < 8; ++i) { s += v[i]; sq += v[i] * v[i]; }
#pragma unroll
  for (int m = 1; m < 64; m <<= 1) { s += __shfl_xor(s, m); sq += __shfl_xor(sq, m); }
  const float mu = s * (1.f / 512.f);
  const float iv = rsqrtf(sq * (1.f / 512.f) - mu * mu + LN_EPS);
  const float4 g0 = ld4(f.ln1g + e), g1 = ld4(f.ln1g + e + 4);
  const float4 b0 = ld4(f.ln1b + e), b1 = ld4(f.ln1b + e + 4);
  const float gg[8] = {g0.x, g0.y, g0.z, g0.w, g1.x, g1.y, g1.z, g1.w};
  const float bb[8] = {b0.x, b0.y, b0.z, b0.w, b1.x, b1.y, b1.z, b1.w};
  float o[8], osq[8];
#pragma unroll
  for (int i = 0; i < 8; ++i) {
    o[i] = (v[i] - mu) * iv * gg[i] + bb[i];
    osq[i] = o[i] * o[i];
  }
  *(uint4*)(f.cb_bf + (long)row * 512 + e) = pack8(o);
  *(uint4*)(f.cbsq_bf + (long)row * 512 + e) = pack8(osq);
}

__device__ __forceinline__ void a96_unit(const FA& f, int u, int t) {
  const int lane = t & 63, e = lane * 8;
  const int bl = u * 4 + (t >> 6);
  const int b = bl >> 5, l = bl & 31;
  const float4 ga0 = ld4(f.gam + (long)bl * 512 + e), ga1 = ld4(f.gam + (long)bl * 512 + e + 4);
  const float4 be0 = ld4(f.bet + (long)bl * 512 + e), be1 = ld4(f.bet + (long)bl * 512 + e + 4);
  const float gv[8] = {ga0.x, ga0.y, ga0.z, ga0.w, ga1.x, ga1.y, ga1.z, ga1.w};
  const float bv[8] = {be0.x, be0.y, be0.z, be0.w, be1.x, be1.y, be1.z, be1.w};
  float gg[8], gb[8]; float s1 = 0.f, s2 = 0.f;
#pragma unroll
  for (int i = 0; i < 8; ++i) {
    gg[i] = gv[i] * gv[i]; gb[i] = gv[i] * bv[i];
    s1 += bv[i]; s2 += bv[i] * bv[i];
  }
  const long basei = ((long)b * 96 + l) * 512 + e;
  *(uint4*)(f.A96_bf + basei) = pack8(gv);                // rows  0..31 : g    (vs cb)
  *(uint4*)(f.A96_bf + basei + 32 * 512) = pack8(gb);     // rows 32..63 : g·be (vs cb)
  *(uint4*)(f.A96_bf + basei + 64 * 512) = pack8(gg);     // rows 64..95 : g²   (vs cb²)
#pragma unroll
  for (int m = 1; m < 64; m <<= 1) { s1 += __shfl_xor(s1, m); s2 += __shfl_xor(s2, m); }
  if (lane == 0) { f.sum_be[bl] = s1; f.sum_be2[bl] = s2; }
}

__device__ __forceinline__ void w1_unit(const FA& f, int u, int t) {
  const int lane = t & 63, e = lane * 8;
  const int lh = u * 4 + (t >> 6);
  const int bl = lh >> 3;
  const uint4 up = *(const uint4*)(f.u_bf + (long)lh * 512 + e);
  const u16* us = (const u16*)&up;
  const float4 ga0 = ld4(f.gam + (long)bl * 512 + e), ga1 = ld4(f.gam + (long)bl * 512 + e + 4);
  const float4 be0 = ld4(f.bet + (long)bl * 512 + e), be1 = ld4(f.bet + (long)bl * 512 + e + 4);
  const float4 G0 = ld4(f.ln2g + e), G1 = ld4(f.ln2g + e + 4);
  const float4 B0 = ld4(f.ln2b + e), B1 = ld4(f.ln2b + e + 4);
  const float gv[8] = {ga0.x, ga0.y, ga0.z, ga0.w, ga1.x, ga1.y, ga1.z, ga1.w};
  const float bv[8] = {be0.x, be0.y, be0.z, be0.w, be1.x, be1.y, be1.z, be1.w};
  const float Gv[8] = {G0.x, G0.y, G0.z, G0.w, G1.x, G1.y, G1.z, G1.w};
  const float Bv[8] = {B0.x, B0.y, B0.z, B0.w, B1.x, B1.y, B1.z, B1.w};
  float wv[8]; float a2 = 0.f, a3 = 0.f, a4 = 0.f;
#pragma unroll
  for (int i = 0; i < 8; ++i) {
    const float uu = b2f(us[i]);
    const float t1 = Gv[i] * uu;
    wv[i] = gv[i] * t1;
    a2 += bv[i] * t1; a3 += t1; a4 += Bv[i] * uu;
  }
  *(uint4*)(f.w1_bf + (long)lh * 512 + e) = pack8(wv);
#pragma unroll
  for (int m = 1; m < 64; m <<= 1) {
    a2 += __shfl_xor(a2, m); a3 += __shfl_xor(a3, m); a4 += __shfl_xor(a4, m);
  }
  if (lane == 0) { f.c2[lh] = a2; f.c3[lh] = a3; f.c4[lh] = a4; }
}

__device__ __forceinline__ void softmax_unit(const FA& f, int u, int t) {
  const int lane = t & 63, e = lane * 4;
  const int lh = u * 4 + (t >> 6);
  const int b = lh >> 8, l = (lh >> 3) & 31, bl = lh >> 3;
  const float4 lg = ld4(f.logits + (long)lh * 256 + e);
  const float* Pb = f.P + ((long)b * 96 + l) * 256 + e;
  const float4 p0 = ld4(Pb), pgb = ld4(Pb + 32 * 256), pg2 = ld4(Pb + 64 * 256);
  const float sbe = f.sum_be[bl], sbe2 = f.sum_be2[bl];
  const float lgs[4] = {lg.x, lg.y, lg.z, lg.w};
  const float p0s[4] = {p0.x, p0.y, p0.z, p0.w};
  const float pgbs[4] = {pgb.x, pgb.y, pgb.z, pgb.w};
  const float pg2s[4] = {pg2.x, pg2.y, pg2.z, pg2.w};
  float mu[4], iv[4];
#pragma unroll
  for (int i = 0; i < 4; ++i) {
    mu[i] = (p0s[i] + sbe) * (1.f / 512.f);
    const float msq = (pg2s[i] + 2.f * pgbs[i] + sbe2) * (1.f / 512.f);
    iv[i] = rsqrtf(msq - mu[i] * mu[i] + LN_EPS);
  }
  float mx = fmaxf(fmaxf(lgs[0], lgs[1]), fmaxf(lgs[2], lgs[3]));
#pragma unroll
  for (int m = 1; m < 64; m <<= 1) mx = fmaxf(mx, __shfl_xor(mx, m));
  float ex[4]; float z = 0.f;
#pragma unroll
  for (int i = 0; i < 4; ++i) { ex[i] = expf(lgs[i] - mx); z += ex[i]; }
#pragma unroll
  for (int m = 1; m < 64; m <<= 1) z += __shfl_xor(z, m);
  const float rz = 1.f / z;
  float wv[4], w1v[4]; float s1 = 0.f, s2 = 0.f;
#pragma unroll
  for (int i = 0; i < 4; ++i) {
    wv[i] = ex[i] * rz;
    w1v[i] = wv[i] * iv[i];
    s1 += w1v[i]; s2 += w1v[i] * mu[i];
  }
  uint2 wp, w1p;
  wp.x = pk2(wv[0], wv[1]); wp.y = pk2(wv[2], wv[3]);
  w1p.x = pk2(w1v[0], w1v[1]); w1p.y = pk2(w1v[2], w1v[3]);
  *(uint2*)(f.w_bf + (long)lh * 256 + e) = wp;
  *(uint2*)(f.W1_bf + (long)lh * 256 + e) = w1p;
#pragma unroll
  for (int m = 1; m < 64; m <<= 1) { s1 += __shfl_xor(s1, m); s2 += __shfl_xor(s2, m); }
  if (lane == 0) { f.S1[lh] = s1; f.S2[lh] = s2; }
}

// ===========================================================================
// Phase executor — shared by the cooperative mega-kernel and the fallback.
// Unit counts: {2496, 704, 1664, 1664, 256, 1024, 512, 64, 64}
// ===========================================================================
__device__ void run_phase(const FA& f, int ph, int u, int t, char* smem) {
  u16* As  = (u16*)smem;
  u16* Bs  = (u16*)(smem + 8192);
  u16* As2 = (u16*)(smem + 16384);
  u16* Bs2 = (u16*)(smem + 24576);
  float (*T)[65] = (float(*)[65])smem;

  switch (ph) {
    case 0: {  // prep: copies (1920) + WkT (64) + kT (512)
      if (u < 1920) {
        const float* s; u16* d; int r = u;
        if (r < 128)      { s = f.q;   d = f.q_bf; }
        else if (r < 384) { s = f.Wg;  d = f.Wg_bf;  r -= 128; }
        else if (r < 512) { s = f.Wq;  d = f.Wq_bf;  r -= 384; }
        else if (r < 640) { s = f.Wvp; d = f.Wvp_bf; r -= 512; }
        else if (r < 768) { s = f.Wv;  d = f.Wv_bf;  r -= 640; }
        else if (r < 896) { s = f.Wfc; d = f.Wfc_bf; r -= 768; }
        else              { s = f.k;   d = f.k_bf;   r -= 896; }
        const long idx = (long)r * 2048 + t * 8;
        const float4 x0 = ld4(s + idx), x1 = ld4(s + idx + 4);
        const float v[8] = {x0.x, x0.y, x0.z, x0.w, x1.x, x1.y, x1.z, x1.w};
        *(uint4*)(d + idx) = pack8(v);
      } else if (u < 1984) {
        const int tt = u - 1920;
        tpf32_unit(f.Wk, 512, f.WkT_bf, 512, tt >> 3, tt & 7, t, T);
      } else {
        const int tt = u - 1984;
        const int b = tt >> 5, w32 = tt & 31;
        tpf32_unit(f.k + (long)b * 131072, 512, f.kT_bf + (long)b * 131072, 256,
                   w32 >> 3, w32 & 7, t, T);
      }
    } break;

    case 1: {  // G2 (512) + G1a (128) + G1b (64)
      GA a = {};
      int bx, by;
      if (u < 512) {
        a.A = f.k_bf; a.lda = 512; a.B = f.Wvp_bf; a.ldb = 512;
        a.Cf = f.condpre; a.ldc = 512; a.M = 4096; a.K = 512; a.epi = 4; a.e0 = f.bvp;
        bx = u % 64; by = u / 64;
      } else if (u < 640) {
        const int r = u - 512;
        a.A = f.q_bf; a.lda = 512; a.B = f.Wg_bf; a.ldb = 512;
        a.Cf = f.gam; a.Cf2 = f.bet; a.ldc = 512; a.M = 512; a.K = 512; a.epi = 2; a.e0 = f.bg;
        bx = r % 8; by = r / 8;
      } else {
        const int r = u - 640;
        a.A = f.q_bf; a.lda = 512; a.B = f.Wq_bf; a.ldb = 512;
        a.Cb = f.qh_bf; a.ldc = 512; a.M = 512; a.K = 512; a.epi = 1;
        bx = r % 8; by = r / 8;
      }
      gemm_core(a, As, Bs, bx, by, 0, t);
    } break;

    case 2: {  // LN (1024) + A96 (128) + Gu (512)
      if (u < 1024) {
        ln_unit(f, u, t);
      } else if (u < 1152) {
        a96_unit(f, u - 1024, t);
      } else {
        const int r = u - 1152;
        GA a = {};
        a.A = f.qh_bf; a.lda = 512; a.sAz = 64;
        a.B = f.WkT_bf; a.ldb = 512; a.sBz = 64;
        a.Cb = f.u_bf; a.ldc = 512; a.M = 512; a.K = 64; a.epi = 5;
        gemm_core(a, As, Bs, r % 8, (r / 8) % 8, r / 64, t);
      }
    } break;

    case 3: {  // GP (128) + cbT (512) + w1 (1024)
      if (u < 128) {
        GA a = {};
        a.A = f.A96_bf; a.lda = 512; a.sAz = 96 * 512;
        a.B = f.cb_bf; a.Balt = f.cbsq_bf; a.ldb = 512; a.sBz = 256 * 512;
        a.Cf = f.P; a.ldc = 256; a.sCz = 96 * 256; a.M = 96; a.K = 512; a.epi = 0;
        gemm_core(a, As, Bs, u % 2, (u / 2) % 4, u / 8, t);
      } else if (u < 640) {
        const int tt = u - 128;
        tpb16_unit(f.cb_bf, f.cbT_bf, tt >> 5, tt & 31, t, T);
      } else {
        w1_unit(f, u - 640, t);
      }
    } break;

    case 4: {  // GK (256): K1=u@k^T, K2=w1@cb^T, logits epilogue
      GA2 d = {};
      d.A1 = f.u_bf; d.A2 = f.w1_bf; d.B1 = f.k_bf; d.B2 = f.cb_bf;
      d.lda = 512; d.ldb = 512; d.sAz = 256 * 512; d.sBz = 256 * 512;
      d.Cf = f.logits; d.ldc = 256; d.sCz = 256 * 256; d.M = 256; d.K = 512;
      d.e1 = f.P; d.e2 = f.sum_be; d.e3 = f.sum_be2; d.e4 = f.c2; d.e5 = f.c3; d.e6 = f.c4;
      gemm2_core(d, As, As2, Bs, Bs2, u % 4, (u / 4) % 4, u / 16, t, 0);
    } break;

    case 5:  // softmax (1024)
      softmax_unit(f, u, t);
      break;

    case 6: {  // GT (512): T1=w@kT^T, T2=W1@cbT^T, s epilogue
      GA2 d = {};
      d.A1 = f.w_bf; d.A2 = f.W1_bf; d.B1 = f.kT_bf; d.B2 = f.cbT_bf;
      d.lda = 256; d.ldb = 256; d.sAz = 256 * 256; d.sBz = 512 * 256;
      d.Cb = f.s_bf; d.ldc = 512; d.sCz = 256 * 512; d.M = 256; d.K = 256;
      d.e1 = f.ln2g; d.e2 = f.ln2b; d.e3 = f.gam; d.e4 = f.bet; d.e5 = f.S1; d.e6 = f.S2;
      gemm2_core(d, As, As2, Bs, Bs2, u % 4, (u / 4) % 8, u / 32, t, 1);
    } break;

    case 7: {  // attn = s_h @ Wv_h^T (64)
      GA a = {};
      a.A = f.s_bf; a.lda = 4096; a.sAz = 512;
      a.B = f.Wv_bf; a.ldb = 512; a.sBz = 64 * 512;
      a.Cb = f.attn_bf; a.ldc = 512; a.sCz = 64; a.M = 512; a.K = 512; a.epi = 1;
      gemm_core(a, As, Bs, u % 8, 0, u / 8, t);
    } break;

    case 8: {  // out = attn @ Wfc^T (64)
      GA a = {};
      a.A = f.attn_bf; a.lda = 512; a.B = f.Wfc_bf; a.ldb = 512;
      a.Cf = f.out; a.ldc = 512; a.M = 512; a.K = 512; a.epi = 0;
      gemm_core(a, As, Bs, u % 8, u / 8, 0, t);
    } break;
  }
}

// Cooperative mega-kernel: 512 persistent blocks (2/CU guaranteed), 8 grid syncs.
__global__ __launch_bounds__(256, 2) void fused_k(FA fa) {
  cg::grid_group grid = cg::this_grid();
  __shared__ __align__(16) char smem[32768];
  const int NU[9] = {2496, 704, 1664, 1664, 256, 1024, 512, 64, 64};
#pragma unroll 1
  for (int p = 0; p < 9; ++p) {
    for (int u = blockIdx.x; u < NU[p]; u += gridDim.x)
      run_phase(fa, p, u, threadIdx.x, smem);
    if (p < 8) grid.sync();
  }
}

// Fallback: one ordinary dispatch per phase (same units, bitwise-identical math).
__global__ __launch_bounds__(256) void phase_k(FA fa, int ph) {
  __shared__ __align__(16) char smem[32768];
  run_phase(fa, ph, blockIdx.x, threadIdx.x, smem);
}

}  // namespace

extern "C" void kernel_launch(void* const* d_in, const int* in_sizes, int n_in,
                              void* d_out, int out_size, void* d_ws, size_t ws_size,
                              hipStream_t stream) {
  (void)in_sizes; (void)n_in; (void)out_size;
  FA fa;
  fa.q    = (const float*)d_in[0];
  fa.k    = (const float*)d_in[1];
  fa.Wq   = (const float*)d_in[3];
  fa.Wk   = (const float*)d_in[4];
  fa.Wv   = (const float*)d_in[5];
  fa.Wfc  = (const float*)d_in[6];
  fa.Wg   = (const float*)d_in[7];
  fa.bg   = (const float*)d_in[8];
  fa.Wvp  = (const float*)d_in[9];
  fa.bvp  = (const float*)d_in[10];
  fa.ln1g = (const float*)d_in[11];
  fa.ln1b = (const float*)d_in[12];
  fa.ln2g = (const float*)d_in[13];
  fa.ln2b = (const float*)d_in[14];
  fa.out  = (float*)d_out;

  // ---- workspace layout (bump allocator, identical sizes to rounds 3-5) ----
  char* base = (char*)d_ws;
  size_t off = 0;
  auto au16 = [&](size_t n) -> u16* {
    u16* p = (u16*)(base + off); off = (off + n * 2 + 255) & ~(size_t)255; return p;
  };
  auto af32 = [&](size_t n) -> float* {
    float* p = (float*)(base + off); off = (off + n * 4 + 255) & ~(size_t)255; return p;
  };
  fa.q_bf    = au16(262144);
  fa.Wg_bf   = au16(524288);
  fa.Wq_bf   = au16(262144);
  fa.Wvp_bf  = au16(262144);
  fa.WkT_bf  = au16(262144);
  fa.Wv_bf   = au16(262144);
  fa.Wfc_bf  = au16(262144);
  fa.k_bf    = au16(2097152);
  fa.kT_bf   = au16(2097152);
  fa.qh_bf   = au16(262144);
  fa.gam     = af32(262144);
  fa.bet     = af32(262144);
  fa.condpre = af32(2097152);
  fa.cb_bf   = au16(2097152);
  fa.cbT_bf  = au16(2097152);
  fa.u_bf    = au16(2097152);
  fa.w1_bf   = au16(2097152);
  fa.c2      = af32(4096);
  fa.c3      = af32(4096);
  fa.c4      = af32(4096);
  fa.A96_bf  = au16(16 * 96 * 512);
  fa.sum_be  = af32(512);
  fa.sum_be2 = af32(512);
  fa.P       = af32(16 * 96 * 256);
  float* sbuf   = af32(1048576);
  float* logits = af32(1048576);
  fa.w_bf    = au16(1048576);
  fa.W1_bf   = au16(1048576);
  fa.S1      = af32(4096);
  fa.S2      = af32(4096);
  fa.attn_bf = au16(262144);
  const size_t need = off;
  fa.s_bf    = (u16*)sbuf;
  fa.logits  = logits;
  fa.cbsq_bf = (u16*)logits;  // cb² lives here until GK overwrites with logits

  if (ws_size < need) return;  // fail loudly via validation

  // Try the cooperative mega-kernel first (enqueue errors return synchronously).
  void* args[] = {(void*)&fa};
  hipError_t err = hipLaunchCooperativeKernel((const void*)fused_k, dim3(512), dim3(256),
                                              args, 0u, stream);
  if (err != hipSuccess) {
    // Fallback: 9 ordinary dispatches, one per phase (identical math).
    static const int NU[9] = {2496, 704, 1664, 1664, 256, 1024, 512, 64, 64};
    for (int p = 0; p < 9; ++p)
      phase_k<<<dim3(NU[p]), dim3(256), 0, stream>>>(fa, p);
  }
}

// Round 7
// 82.290 us; speedup vs baseline: 6.7143x; 6.7143x over previous
//
#include <hip/hip_runtime.h>
#include <math.h>

namespace {
constexpr float LN_EPS = 1e-5f;

typedef unsigned short u16;
typedef __attribute__((ext_vector_type(8))) short bh8;
typedef __attribute__((ext_vector_type(4))) float fv4;

__device__ __forceinline__ float4 ld4(const float* p) { return *reinterpret_cast<const float4*>(p); }

__device__ __forceinline__ float b2f(u16 x) {
  union { float f; unsigned u; } c; c.u = ((unsigned)x) << 16; return c.f;
}
__device__ __forceinline__ u16 f2b(float f) {  // RTN-even
  union { float f; unsigned u; } c; c.f = f;
  unsigned u = c.u;
  u += 0x7FFFu + ((u >> 16) & 1u);
  return (u16)(u >> 16);
}
__device__ __forceinline__ unsigned pk2(float a, float b) {
  return (unsigned)f2b(a) | ((unsigned)f2b(b) << 16);
}
__device__ __forceinline__ uint4 pack8(const float* v) {
  uint4 r; r.x = pk2(v[0], v[1]); r.y = pk2(v[2], v[3]); r.z = pk2(v[4], v[5]); r.w = pk2(v[6], v[7]);
  return r;
}

// XOR-swizzled LDS tile access: [64][64] u16, 16B slots, c8 ^= row&7
__device__ __forceinline__ bh8 lds_rd(const u16* S, int row, int c8) {
  return *(const bh8*)&S[row * 64 + ((c8 ^ (row & 7)) << 3)];
}

struct FA {
  const float *q, *k, *Wq, *Wk, *Wv, *Wfc, *Wg, *bg, *Wvp, *bvp;
  const float *ln1g, *ln1b, *ln2g, *ln2b;
  float* out;
  u16 *WkT_bf, *Wv_bf, *Wfc_bf, *k_bf, *kT_bf, *qh_bf;
  float *gam, *bet, *condpre;
  u16 *cb_bf, *cbT_bf, *u_bf, *w1_bf;
  float *c2, *c3, *c4;
  u16* A96_bf;
  float *sum_be, *sum_be2, *P;
  u16* s_bf;
  u16 *cbsq_bf, *w_bf, *W1_bf;
  float *S1, *S2;
  u16* attn_bf;
  float *K1, *K2;
};

// ===========================================================================
// bf16 GEMM core (verified rounds 4-6). epi: 0 f32, 1 bf16, 5 u-remap,
// 6 u-remap + fused w1 (e0=gam row-indexed, e1=ln2g, Cb2=w1 out)
// ===========================================================================
struct GA {
  const u16* A; const u16* B; const u16* Balt;
  long lda, ldb, sAz, sBz;
  float* Cf; u16* Cb; u16* Cb2;
  long ldc, sCz;
  int M, K, epi;
  const float* e0; const float* e1;
};

__device__ __forceinline__ void gemm_core(const GA& a, u16* As, u16* Bs,
                                          int bx, int by, int bz, int t) {
  const int z = bz;
  const int bm0 = bx * 64, bn0 = by * 64;
  const int lane = t & 63, w = t >> 6;
  const int wm = (w >> 1) * 32, wn = (w & 1) * 32;
  const u16* Ab = a.A + (long)z * a.sAz;
  const u16* Bbase = (a.Balt != nullptr && bm0 >= 64) ? a.Balt : a.B;
  const u16* Bb = Bbase + (long)z * a.sBz;

  const int sr = t >> 3, sc8 = t & 7, sc = sc8 * 8;
  int ar0 = bm0 + sr;      if (ar0 > a.M - 1) ar0 = a.M - 1;
  int ar1 = bm0 + sr + 32; if (ar1 > a.M - 1) ar1 = a.M - 1;
  const u16* ap0 = Ab + (long)ar0 * a.lda + sc;
  const u16* ap1 = Ab + (long)ar1 * a.lda + sc;
  const u16* bp0 = Bb + (long)(bn0 + sr) * a.ldb + sc;
  const u16* bp1 = Bb + (long)(bn0 + sr + 32) * a.ldb + sc;
  const int iA0 = sr * 64 + ((sc8 ^ (sr & 7)) << 3);
  const int iA1 = iA0 + 32 * 64;

  fv4 zero = {0.f, 0.f, 0.f, 0.f};
  fv4 acc00 = zero, acc01 = zero, acc10 = zero, acc11 = zero;
  const int r0 = lane & 15, kq8 = lane >> 4;
  const int nk = a.K >> 6;

  uint4 av0 = *(const uint4*)ap0, av1 = *(const uint4*)ap1;
  uint4 bv0 = *(const uint4*)bp0, bv1 = *(const uint4*)bp1;
  for (int kt = 0; kt < nk; ++kt) {
    __syncthreads();
    *(uint4*)&As[iA0] = av0; *(uint4*)&As[iA1] = av1;
    *(uint4*)&Bs[iA0] = bv0; *(uint4*)&Bs[iA1] = bv1;
    __syncthreads();
    if (kt + 1 < nk) {
      ap0 += 64; ap1 += 64; bp0 += 64; bp1 += 64;
      av0 = *(const uint4*)ap0; av1 = *(const uint4*)ap1;
      bv0 = *(const uint4*)bp0; bv1 = *(const uint4*)bp1;
    }
#pragma unroll
    for (int kc = 0; kc < 2; ++kc) {
      const int c8 = kq8 + 4 * kc;
      bh8 aa0 = lds_rd(As, wm + r0, c8);
      bh8 aa1 = lds_rd(As, wm + 16 + r0, c8);
      bh8 bb0 = lds_rd(Bs, wn + r0, c8);
      bh8 bb1 = lds_rd(Bs, wn + 16 + r0, c8);
      acc00 = __builtin_amdgcn_mfma_f32_16x16x32_bf16(aa0, bb0, acc00, 0, 0, 0);
      acc01 = __builtin_amdgcn_mfma_f32_16x16x32_bf16(aa0, bb1, acc01, 0, 0, 0);
      acc10 = __builtin_amdgcn_mfma_f32_16x16x32_bf16(aa1, bb0, acc10, 0, 0, 0);
      acc11 = __builtin_amdgcn_mfma_f32_16x16x32_bf16(aa1, bb1, acc11, 0, 0, 0);
    }
  }

  fv4 accs[2][2] = {{acc00, acc01}, {acc10, acc11}};
#pragma unroll
  for (int rb = 0; rb < 2; ++rb) {
#pragma unroll
    for (int cbl = 0; cbl < 2; ++cbl) {
#pragma unroll
      for (int j = 0; j < 4; ++j) {
        const int r = bm0 + wm + rb * 16 + (lane >> 4) * 4 + j;
        const int c = bn0 + wn + cbl * 16 + (lane & 15);
        if (r >= a.M) continue;
        const float v = accs[rb][cbl][j];
        if (a.epi == 0) {
          a.Cf[(long)z * a.sCz + (long)r * a.ldc + c] = v;
        } else if (a.epi == 1) {
          a.Cb[(long)z * a.sCz + (long)r * a.ldc + c] = f2b(v);
        } else if (a.epi == 5) {  // u remap, *0.125
          a.Cb[((long)r * 8 + z) * a.ldc + c] = f2b(v * 0.125f);
        } else {  // 6: u remap + fused w1 (bitwise-identical to old w1_unit)
          const u16 ub = f2b(v * 0.125f);
          const long orow = (long)r * 8 + z;
          a.Cb[orow * 512 + c] = ub;
          const float uu = b2f(ub);
          const float t1 = a.e1[c] * uu;                    // ln2g * u
          a.Cb2[orow * 512 + c] = f2b(a.e0[(long)r * 512 + c] * t1);  // gam * (ln2g*u)
        }
      }
    }
  }
}

// ===========================================================================
// f32-staging GEMM core: inputs are f32; convert (same RTN f2b) during staging.
// epi: 1 bf16 store, 2 film(tanh,split e0=bias, Cf=gam, Cb2 unused -> Cf2), 4 +bias f32
// ===========================================================================
struct GAF {
  const float* Af; const float* Bf;
  long lda, ldb;
  float* Cf; u16* Cb; float* Cf2;
  long ldc;
  int M, K, epi;
  const float* e0;
};

__device__ __forceinline__ void gemm_core_f32(const GAF& a, u16* As, u16* Bs,
                                              int bx, int by, int t) {
  const int bm0 = bx * 64, bn0 = by * 64;
  const int lane = t & 63, w = t >> 6;
  const int wm = (w >> 1) * 32, wn = (w & 1) * 32;
  const int sr = t >> 3, sc8 = t & 7, sc = sc8 * 8;
  int ar0 = bm0 + sr;      if (ar0 > a.M - 1) ar0 = a.M - 1;
  int ar1 = bm0 + sr + 32; if (ar1 > a.M - 1) ar1 = a.M - 1;
  const float* ap0 = a.Af + (long)ar0 * a.lda + sc;
  const float* ap1 = a.Af + (long)ar1 * a.lda + sc;
  const float* bp0 = a.Bf + (long)(bn0 + sr) * a.ldb + sc;
  const float* bp1 = a.Bf + (long)(bn0 + sr + 32) * a.ldb + sc;
  const int iA0 = sr * 64 + ((sc8 ^ (sr & 7)) << 3);
  const int iA1 = iA0 + 32 * 64;

  fv4 zero = {0.f, 0.f, 0.f, 0.f};
  fv4 acc00 = zero, acc01 = zero, acc10 = zero, acc11 = zero;
  const int r0 = lane & 15, kq8 = lane >> 4;
  const int nk = a.K >> 6;

  float4 xa0 = ld4(ap0), xa1 = ld4(ap0 + 4), xa2 = ld4(ap1), xa3 = ld4(ap1 + 4);
  float4 xb0 = ld4(bp0), xb1 = ld4(bp0 + 4), xb2 = ld4(bp1), xb3 = ld4(bp1 + 4);
  for (int kt = 0; kt < nk; ++kt) {
    __syncthreads();
    {
      const float v0[8] = {xa0.x, xa0.y, xa0.z, xa0.w, xa1.x, xa1.y, xa1.z, xa1.w};
      const float v1[8] = {xa2.x, xa2.y, xa2.z, xa2.w, xa3.x, xa3.y, xa3.z, xa3.w};
      const float v2[8] = {xb0.x, xb0.y, xb0.z, xb0.w, xb1.x, xb1.y, xb1.z, xb1.w};
      const float v3[8] = {xb2.x, xb2.y, xb2.z, xb2.w, xb3.x, xb3.y, xb3.z, xb3.w};
      *(uint4*)&As[iA0] = pack8(v0);
      *(uint4*)&As[iA1] = pack8(v1);
      *(uint4*)&Bs[iA0] = pack8(v2);
      *(uint4*)&Bs[iA1] = pack8(v3);
    }
    __syncthreads();
    if (kt + 1 < nk) {
      ap0 += 64; ap1 += 64; bp0 += 64; bp1 += 64;
      xa0 = ld4(ap0); xa1 = ld4(ap0 + 4); xa2 = ld4(ap1); xa3 = ld4(ap1 + 4);
      xb0 = ld4(bp0); xb1 = ld4(bp0 + 4); xb2 = ld4(bp1); xb3 = ld4(bp1 + 4);
    }
#pragma unroll
    for (int kc = 0; kc < 2; ++kc) {
      const int c8 = kq8 + 4 * kc;
      bh8 aa0 = lds_rd(As, wm + r0, c8);
      bh8 aa1 = lds_rd(As, wm + 16 + r0, c8);
      bh8 bb0 = lds_rd(Bs, wn + r0, c8);
      bh8 bb1 = lds_rd(Bs, wn + 16 + r0, c8);
      acc00 = __builtin_amdgcn_mfma_f32_16x16x32_bf16(aa0, bb0, acc00, 0, 0, 0);
      acc01 = __builtin_amdgcn_mfma_f32_16x16x32_bf16(aa0, bb1, acc01, 0, 0, 0);
      acc10 = __builtin_amdgcn_mfma_f32_16x16x32_bf16(aa1, bb0, acc10, 0, 0, 0);
      acc11 = __builtin_amdgcn_mfma_f32_16x16x32_bf16(aa1, bb1, acc11, 0, 0, 0);
    }
  }

  fv4 accs[2][2] = {{acc00, acc01}, {acc10, acc11}};
#pragma unroll
  for (int rb = 0; rb < 2; ++rb) {
#pragma unroll
    for (int cbl = 0; cbl < 2; ++cbl) {
#pragma unroll
      for (int j = 0; j < 4; ++j) {
        const int r = bm0 + wm + rb * 16 + (lane >> 4) * 4 + j;
        const int c = bn0 + wn + cbl * 16 + (lane & 15);
        if (r >= a.M) continue;
        const float v = accs[rb][cbl][j];
        if (a.epi == 1) {
          a.Cb[(long)r * a.ldc + c] = f2b(v);
        } else if (a.epi == 2) {  // film
          const float x = tanhf(v + a.e0[c]);
          if (c < 512) a.Cf[(long)r * 512 + c] = x;
          else         a.Cf2[(long)r * 512 + (c - 512)] = x;
        } else {  // 4: + bias, f32
          a.Cf[(long)r * a.ldc + c] = v + a.e0[c];
        }
      }
    }
  }
}

// ===========================================================================
// Dual batched GEMM. EPI: 1 = s-epilogue (GT), 2 = raw K1/K2 (GK)
// ===========================================================================
struct GA2 {
  const u16* A1; const u16* A2; const u16* B1; const u16* B2;
  long lda, ldb, sAz, sBz;
  float* Cf; float* Cf2; u16* Cb;
  long ldc, sCz;
  int M, K;
  const float* e1; const float* e2; const float* e3;
  const float* e4; const float* e5; const float* e6;
};

__device__ __forceinline__ void gemm2_core(const GA2& a, u16* As1, u16* As2,
                                           u16* Bs1, u16* Bs2,
                                           int bx, int by, int bz, int t, int EPI) {
  const int z = bz;
  const int bm0 = bx * 64, bn0 = by * 64;
  const int lane = t & 63, w = t >> 6;
  const int wm = (w >> 1) * 32, wn = (w & 1) * 32;
  const u16* A1b = a.A1 + (long)z * a.sAz;
  const u16* A2b = a.A2 + (long)z * a.sAz;
  const u16* B1b = a.B1 + (long)z * a.sBz;
  const u16* B2b = a.B2 + (long)z * a.sBz;

  const int sr = t >> 3, sc8 = t & 7, sc = sc8 * 8;
  const long aoff0 = (long)(bm0 + sr) * a.lda + sc;
  const long aoff1 = (long)(bm0 + sr + 32) * a.lda + sc;
  const long boff0 = (long)(bn0 + sr) * a.ldb + sc;
  const long boff1 = (long)(bn0 + sr + 32) * a.ldb + sc;
  const u16 *a1p0 = A1b + aoff0, *a1p1 = A1b + aoff1;
  const u16 *a2p0 = A2b + aoff0, *a2p1 = A2b + aoff1;
  const u16 *b1p0 = B1b + boff0, *b1p1 = B1b + boff1;
  const u16 *b2p0 = B2b + boff0, *b2p1 = B2b + boff1;
  const int iA0 = sr * 64 + ((sc8 ^ (sr & 7)) << 3);
  const int iA1 = iA0 + 32 * 64;

  fv4 zero = {0.f, 0.f, 0.f, 0.f};
  fv4 p00 = zero, p01 = zero, p10 = zero, p11 = zero;
  fv4 q00 = zero, q01 = zero, q10 = zero, q11 = zero;
  const int r0 = lane & 15, kq8 = lane >> 4;
  const int nk = a.K >> 6;

  uint4 a1v0 = *(const uint4*)a1p0, a1v1 = *(const uint4*)a1p1;
  uint4 a2v0 = *(const uint4*)a2p0, a2v1 = *(const uint4*)a2p1;
  uint4 b1v0 = *(const uint4*)b1p0, b1v1 = *(const uint4*)b1p1;
  uint4 b2v0 = *(const uint4*)b2p0, b2v1 = *(const uint4*)b2p1;
  for (int kt = 0; kt < nk; ++kt) {
    __syncthreads();
    *(uint4*)&As1[iA0] = a1v0; *(uint4*)&As1[iA1] = a1v1;
    *(uint4*)&As2[iA0] = a2v0; *(uint4*)&As2[iA1] = a2v1;
    *(uint4*)&Bs1[iA0] = b1v0; *(uint4*)&Bs1[iA1] = b1v1;
    *(uint4*)&Bs2[iA0] = b2v0; *(uint4*)&Bs2[iA1] = b2v1;
    __syncthreads();
    if (kt + 1 < nk) {
      a1p0 += 64; a1p1 += 64; a2p0 += 64; a2p1 += 64;
      b1p0 += 64; b1p1 += 64; b2p0 += 64; b2p1 += 64;
      a1v0 = *(const uint4*)a1p0; a1v1 = *(const uint4*)a1p1;
      a2v0 = *(const uint4*)a2p0; a2v1 = *(const uint4*)a2p1;
      b1v0 = *(const uint4*)b1p0; b1v1 = *(const uint4*)b1p1;
      b2v0 = *(const uint4*)b2p0; b2v1 = *(const uint4*)b2p1;
    }
#pragma unroll
    for (int kc = 0; kc < 2; ++kc) {
      const int c8 = kq8 + 4 * kc;
      bh8 x0 = lds_rd(As1, wm + r0, c8);
      bh8 x1 = lds_rd(As1, wm + 16 + r0, c8);
      bh8 y0 = lds_rd(Bs1, wn + r0, c8);
      bh8 y1 = lds_rd(Bs1, wn + 16 + r0, c8);
      p00 = __builtin_amdgcn_mfma_f32_16x16x32_bf16(x0, y0, p00, 0, 0, 0);
      p01 = __builtin_amdgcn_mfma_f32_16x16x32_bf16(x0, y1, p01, 0, 0, 0);
      p10 = __builtin_amdgcn_mfma_f32_16x16x32_bf16(x1, y0, p10, 0, 0, 0);
      p11 = __builtin_amdgcn_mfma_f32_16x16x32_bf16(x1, y1, p11, 0, 0, 0);
      bh8 u0 = lds_rd(As2, wm + r0, c8);
      bh8 u1 = lds_rd(As2, wm + 16 + r0, c8);
      bh8 v0 = lds_rd(Bs2, wn + r0, c8);
      bh8 v1 = lds_rd(Bs2, wn + 16 + r0, c8);
      q00 = __builtin_amdgcn_mfma_f32_16x16x32_bf16(u0, v0, q00, 0, 0, 0);
      q01 = __builtin_amdgcn_mfma_f32_16x16x32_bf16(u0, v1, q01, 0, 0, 0);
      q10 = __builtin_amdgcn_mfma_f32_16x16x32_bf16(u1, v0, q10, 0, 0, 0);
      q11 = __builtin_amdgcn_mfma_f32_16x16x32_bf16(u1, v1, q11, 0, 0, 0);
    }
  }

  fv4 pa[2][2] = {{p00, p01}, {p10, p11}};
  fv4 qa[2][2] = {{q00, q01}, {q10, q11}};
#pragma unroll
  for (int rb = 0; rb < 2; ++rb) {
#pragma unroll
    for (int cbl = 0; cbl < 2; ++cbl) {
#pragma unroll
      for (int j = 0; j < 4; ++j) {
        const int r = bm0 + wm + rb * 16 + (lane >> 4) * 4 + j;
        const int c = bn0 + wn + cbl * 16 + (lane & 15);
        if (r >= a.M) continue;
        const float v1 = pa[rb][cbl][j];
        const float v2 = qa[rb][cbl][j];
        if (EPI == 2) {  // raw K1/K2
          const long idx = (long)z * a.sCz + (long)r * a.ldc + c;
          a.Cf[idx] = v1;
          a.Cf2[idx] = v2;
        } else {  // s: v1=T1, v2=T2
          const int lh = z * 256 + r;
          const int bl = z * 32 + (r >> 3);
          const float G2d = a.e1[c], B2d = a.e2[c];
          const float gv = a.e3[(long)bl * 512 + c];
          const float bev = a.e4[(long)bl * 512 + c];
          const float sv = v1 + B2d + G2d * (gv * v2 + bev * a.e5[lh] - a.e6[lh]);
          a.Cb[(long)z * a.sCz + (long)r * a.ldc + c] = f2b(sv);
        }
      }
    }
  }
}

// ===========================================================================
// Elementwise / transpose units (verified code)
// ===========================================================================
__device__ __forceinline__ void tpf32_unit(const float* src, long lds, u16* dst, long ldd,
                                           int tr, int tc, int t, float T[64][65]) {
  const int c = t & 63, rg = t >> 6;
#pragma unroll 4
  for (int i = 0; i < 16; ++i) {
    const int r = rg + 4 * i;
    T[r][c] = src[(long)(tr * 64 + r) * lds + tc * 64 + c];
  }
  __syncthreads();
#pragma unroll 4
  for (int i = 0; i < 16; ++i) {
    const int r = rg + 4 * i;
    dst[(long)(tc * 64 + r) * ldd + tr * 64 + c] = f2b(T[c][r]);
  }
}

__device__ __forceinline__ void tpb16_unit(const u16* src, u16* dst, int b, int w32,
                                           int t, float T[64][65]) {
  const int tr = w32 >> 3, tc = w32 & 7;
  const u16* s = src + (long)b * 131072;
  u16* d = dst + (long)b * 131072;
  const int c = t & 63, rg = t >> 6;
#pragma unroll 4
  for (int i = 0; i < 16; ++i) {
    const int r = rg + 4 * i;
    T[r][c] = b2f(s[(long)(tr * 64 + r) * 512 + tc * 64 + c]);
  }
  __syncthreads();
#pragma unroll 4
  for (int i = 0; i < 16; ++i) {
    const int r = rg + 4 * i;
    d[(long)(tc * 64 + r) * 256 + tr * 64 + c] = f2b(T[c][r]);
  }
}

__device__ __forceinline__ void cvt_unit(const float* s, u16* d, long blk, int t) {
  const long idx = blk * 2048 + t * 8;
  const float4 x0 = ld4(s + idx), x1 = ld4(s + idx + 4);
  const float v[8] = {x0.x, x0.y, x0.z, x0.w, x1.x, x1.y, x1.z, x1.w};
  *(uint4*)(d + idx) = pack8(v);
}

__device__ __forceinline__ void ln_unit(const FA& f, int u, int t) {
  const int lane = t & 63, e = lane * 8;
  const int row = u * 4 + (t >> 6);
  const float* p = f.condpre + (long)row * 512 + e;
  const float4 x0 = ld4(p), x1 = ld4(p + 4);
  float v[8] = {x0.x, x0.y, x0.z, x0.w, x1.x, x1.y, x1.z, x1.w};
  float s = 0.f, sq = 0.f;
#pragma unroll
  for (int i = 0; i < 8; ++i) { s += v[i]; sq += v[i] * v[i]; }
#pragma unroll
  for (int m = 1; m < 64; m <<= 1) { s += __shfl_xor(s, m); sq += __shfl_xor(sq, m); }
  const float mu = s * (1.f / 512.f);
  const float iv = rsqrtf(sq * (1.f / 512.f) - mu * mu + LN_EPS);
  const float4 g0 = ld4(f.ln1g + e), g1 = ld4(f.ln1g + e + 4);
  const float4 b0 = ld4(f.ln1b + e), b1 = ld4(f.ln1b + e + 4);
  const float gg[8] = {g0.x, g0.y, g0.z, g0.w, g1.x, g1.y, g1.z, g1.w};
  const float bb[8] = {b0.x, b0.y, b0.z, b0.w, b1.x, b1.y, b1.z, b1.w};
  float o[8], osq[8];
#pragma unroll
  for (int i = 0; i < 8; ++i) {
    o[i] = (v[i] - mu) * iv * gg[i] + bb[i];
    osq[i] = o[i] * o[i];
  }
  *(uint4*)(f.cb_bf + (long)row * 512 + e) = pack8(o);
  *(uint4*)(f.cbsq_bf + (long)row * 512 + e) = pack8(osq);
}

__device__ __forceinline__ void a96_unit(const FA& f, int u, int t) {
  const int lane = t & 63, e = lane * 8;
  const int bl = u * 4 + (t >> 6);
  const int b = bl >> 5, l = bl & 31;
  const float4 ga0 = ld4(f.gam + (long)bl * 512 + e), ga1 = ld4(f.gam + (long)bl * 512 + e + 4);
  const float4 be0 = ld4(f.bet + (long)bl * 512 + e), be1 = ld4(f.bet + (long)bl * 512 + e + 4);
  const float gv[8] = {ga0.x, ga0.y, ga0.z, ga0.w, ga1.x, ga1.y, ga1.z, ga1.w};
  const float bv[8] = {be0.x, be0.y, be0.z, be0.w, be1.x, be1.y, be1.z, be1.w};
  float gg[8], gb[8]; float s1 = 0.f, s2 = 0.f;
#pragma unroll
  for (int i = 0; i < 8; ++i) {
    gg[i] = gv[i] * gv[i]; gb[i] = gv[i] * bv[i];
    s1 += bv[i]; s2 += bv[i] * bv[i];
  }
  const long basei = ((long)b * 96 + l) * 512 + e;
  *(uint4*)(f.A96_bf + basei) = pack8(gv);
  *(uint4*)(f.A96_bf + basei + 32 * 512) = pack8(gb);
  *(uint4*)(f.A96_bf + basei + 64 * 512) = pack8(gg);
#pragma unroll
  for (int m = 1; m < 64; m <<= 1) { s1 += __shfl_xor(s1, m); s2 += __shfl_xor(s2, m); }
  if (lane == 0) { f.sum_be[bl] = s1; f.sum_be2[bl] = s2; }
}

__device__ __forceinline__ void csum_unit(const FA& f, int u, int t) {
  const int lane = t & 63, e = lane * 8;
  const int lh = u * 4 + (t >> 6);
  const int bl = lh >> 3;
  const uint4 up = *(const uint4*)(f.u_bf + (long)lh * 512 + e);
  const u16* us = (const u16*)&up;
  const float4 be0 = ld4(f.bet + (long)bl * 512 + e), be1 = ld4(f.bet + (long)bl * 512 + e + 4);
  const float4 G0 = ld4(f.ln2g + e), G1 = ld4(f.ln2g + e + 4);
  const float4 B0 = ld4(f.ln2b + e), B1 = ld4(f.ln2b + e + 4);
  const float bv[8] = {be0.x, be0.y, be0.z, be0.w, be1.x, be1.y, be1.z, be1.w};
  const float Gv[8] = {G0.x, G0.y, G0.z, G0.w, G1.x, G1.y, G1.z, G1.w};
  const float Bv[8] = {B0.x, B0.y, B0.z, B0.w, B1.x, B1.y, B1.z, B1.w};
  float a2 = 0.f, a3 = 0.f, a4 = 0.f;
#pragma unroll
  for (int i = 0; i < 8; ++i) {
    const float uu = b2f(us[i]);
    const float t1 = Gv[i] * uu;
    a2 += bv[i] * t1; a3 += t1; a4 += Bv[i] * uu;
  }
#pragma unroll
  for (int m = 1; m < 64; m <<= 1) {
    a2 += __shfl_xor(a2, m); a3 += __shfl_xor(a3, m); a4 += __shfl_xor(a4, m);
  }
  if (lane == 0) { f.c2[lh] = a2; f.c3[lh] = a3; f.c4[lh] = a4; }
}

// softmax + logits assembly (reads raw K1/K2)
__device__ __forceinline__ void softmax2_unit(const FA& f, int u, int t) {
  const int lane = t & 63, e = lane * 4;
  const int lh = u * 4 + (t >> 6);
  const int b = lh >> 8, l = (lh >> 3) & 31, bl = lh >> 3;
  const float4 k1 = ld4(f.K1 + (long)lh * 256 + e);
  const float4 k2 = ld4(f.K2 + (long)lh * 256 + e);
  const float* Pb = f.P + ((long)b * 96 + l) * 256 + e;
  const float4 p0 = ld4(Pb), pgb = ld4(Pb + 32 * 256), pg2 = ld4(Pb + 64 * 256);
  const float sbe = f.sum_be[bl], sbe2 = f.sum_be2[bl];
  const float C2 = f.c2[lh], C3 = f.c3[lh], C4 = f.c4[lh];
  const float k1s[4] = {k1.x, k1.y, k1.z, k1.w};
  const float k2s[4] = {k2.x, k2.y, k2.z, k2.w};
  const float p0s[4] = {p0.x, p0.y, p0.z, p0.w};
  const float pgbs[4] = {pgb.x, pgb.y, pgb.z, pgb.w};
  const float pg2s[4] = {pg2.x, pg2.y, pg2.z, pg2.w};
  float mu[4], iv[4], lgs[4];
#pragma unroll
  for (int i = 0; i < 4; ++i) {
    mu[i] = (p0s[i] + sbe) * (1.f / 512.f);
    const float msq = (pg2s[i] + 2.f * pgbs[i] + sbe2) * (1.f / 512.f);
    iv[i] = rsqrtf(msq - mu[i] * mu[i] + LN_EPS);
    lgs[i] = k1s[i] + C4 + iv[i] * (k2s[i] + C2 - mu[i] * C3);
  }
  float mx = fmaxf(fmaxf(lgs[0], lgs[1]), fmaxf(lgs[2], lgs[3]));
#pragma unroll
  for (int m = 1; m < 64; m <<= 1) mx = fmaxf(mx, __shfl_xor(mx, m));
  float ex[4]; float z = 0.f;
#pragma unroll
  for (int i = 0; i < 4; ++i) { ex[i] = expf(lgs[i] - mx); z += ex[i]; }
#pragma unroll
  for (int m = 1; m < 64; m <<= 1) z += __shfl_xor(z, m);
  const float rz = 1.f / z;
  float wv[4], w1v[4]; float s1 = 0.f, s2 = 0.f;
#pragma unroll
  for (int i = 0; i < 4; ++i) {
    wv[i] = ex[i] * rz;
    w1v[i] = wv[i] * iv[i];
    s1 += w1v[i]; s2 += w1v[i] * mu[i];
  }
  uint2 wp, w1p;
  wp.x = pk2(wv[0], wv[1]); wp.y = pk2(wv[2], wv[3]);
  w1p.x = pk2(w1v[0], w1v[1]); w1p.y = pk2(w1v[2], w1v[3]);
  *(uint2*)(f.w_bf + (long)lh * 256 + e) = wp;
  *(uint2*)(f.W1_bf + (long)lh * 256 + e) = w1p;
#pragma unroll
  for (int m = 1; m < 64; m <<= 1) { s1 += __shfl_xor(s1, m); s2 += __shfl_xor(s2, m); }
  if (lane == 0) { f.S1[lh] = s1; f.S2[lh] = s2; }
}

// ===========================================================================
// Phase kernels (7 ordinary dispatches)
// ===========================================================================
// A: G2-f32(512) + G1a-f32(128) + G1b-f32(64) + k cvt(1024) + Wv(128) + Wfc(128)
//    + WkT(64) + kT(512) = 2560
__global__ __launch_bounds__(256) void pA_k(FA f) {
  __shared__ __align__(16) char smem[16704];
  u16* As = (u16*)smem;
  u16* Bs = (u16*)(smem + 8192);
  float (*T)[65] = (float(*)[65])smem;
  const int u = blockIdx.x, t = threadIdx.x;
  if (u < 512) {
    GAF a = {}; a.Af = f.k; a.Bf = f.Wvp; a.lda = 512; a.ldb = 512;
    a.Cf = f.condpre; a.ldc = 512; a.M = 4096; a.K = 512; a.epi = 4; a.e0 = f.bvp;
    gemm_core_f32(a, As, Bs, u % 64, u / 64, t);
  } else if (u < 640) {
    const int r = u - 512;
    GAF a = {}; a.Af = f.q; a.Bf = f.Wg; a.lda = 512; a.ldb = 512;
    a.Cf = f.gam; a.Cf2 = f.bet; a.ldc = 512; a.M = 512; a.K = 512; a.epi = 2; a.e0 = f.bg;
    gemm_core_f32(a, As, Bs, r % 8, r / 8, t);
  } else if (u < 704) {
    const int r = u - 640;
    GAF a = {}; a.Af = f.q; a.Bf = f.Wq; a.lda = 512; a.ldb = 512;
    a.Cb = f.qh_bf; a.ldc = 512; a.M = 512; a.K = 512; a.epi = 1;
    gemm_core_f32(a, As, Bs, r % 8, r / 8, t);
  } else if (u < 1728) {
    cvt_unit(f.k, f.k_bf, u - 704, t);
  } else if (u < 1856) {
    cvt_unit(f.Wv, f.Wv_bf, u - 1728, t);
  } else if (u < 1984) {
    cvt_unit(f.Wfc, f.Wfc_bf, u - 1856, t);
  } else if (u < 2048) {
    const int tt = u - 1984;
    tpf32_unit(f.Wk, 512, f.WkT_bf, 512, tt >> 3, tt & 7, t, T);
  } else {
    const int tt = u - 2048;
    const int b = tt >> 5, w32 = tt & 31;
    tpf32_unit(f.k + (long)b * 131072, 512, f.kT_bf + (long)b * 131072, 256,
               w32 >> 3, w32 & 7, t, T);
  }
}

// B: LN(1024) + A96(128) + Gu·w1(512) = 1664
__global__ __launch_bounds__(256) void pB_k(FA f) {
  __shared__ __align__(16) char smem[16384];
  u16* As = (u16*)smem;
  u16* Bs = (u16*)(smem + 8192);
  const int u = blockIdx.x, t = threadIdx.x;
  if (u < 1024) {
    ln_unit(f, u, t);
  } else if (u < 1152) {
    a96_unit(f, u - 1024, t);
  } else {
    const int r = u - 1152;
    GA a = {}; a.A = f.qh_bf; a.lda = 512; a.sAz = 64;
    a.B = f.WkT_bf; a.ldb = 512; a.sBz = 64;
    a.Cb = f.u_bf; a.Cb2 = f.w1_bf; a.ldc = 512; a.M = 512; a.K = 64; a.epi = 6;
    a.e0 = f.gam; a.e1 = f.ln2g;
    gemm_core(a, As, Bs, r % 8, (r / 8) % 8, r / 64, t);
  }
}

// C: GP(128) + cbT(512) + csum(1024) + GK-raw(256) = 1920
__global__ __launch_bounds__(256) void pC_k(FA f) {
  __shared__ __align__(16) char smem[32768];
  const int u = blockIdx.x, t = threadIdx.x;
  if (u < 128) {
    u16* As = (u16*)smem; u16* Bs = (u16*)(smem + 8192);
    GA a = {}; a.A = f.A96_bf; a.lda = 512; a.sAz = 96 * 512;
    a.B = f.cb_bf; a.Balt = f.cbsq_bf; a.ldb = 512; a.sBz = 256 * 512;
    a.Cf = f.P; a.ldc = 256; a.sCz = 96 * 256; a.M = 96; a.K = 512; a.epi = 0;
    gemm_core(a, As, Bs, u % 2, (u / 2) % 4, u / 8, t);
  } else if (u < 640) {
    float (*T)[65] = (float(*)[65])smem;
    const int tt = u - 128;
    tpb16_unit(f.cb_bf, f.cbT_bf, tt >> 5, tt & 31, t, T);
  } else if (u < 1664) {
    csum_unit(f, u - 640, t);
  } else {
    const int r = u - 1664;
    u16* As1 = (u16*)smem; u16* As2 = (u16*)(smem + 8192);
    u16* Bs1 = (u16*)(smem + 16384); u16* Bs2 = (u16*)(smem + 24576);
    GA2 d = {};
    d.A1 = f.u_bf; d.A2 = f.w1_bf; d.B1 = f.k_bf; d.B2 = f.cb_bf;
    d.lda = 512; d.ldb = 512; d.sAz = 256 * 512; d.sBz = 256 * 512;
    d.Cf = f.K1; d.Cf2 = f.K2; d.ldc = 256; d.sCz = 256 * 256; d.M = 256; d.K = 512;
    gemm2_core(d, As1, As2, Bs1, Bs2, r % 4, (r / 4) % 4, r / 16, t, 2);
  }
}

// D: softmax + logits assembly (1024)
__global__ __launch_bounds__(256) void pD_k(FA f) {
  softmax2_unit(f, blockIdx.x, threadIdx.x);
}

// E: GT (512)
__global__ __launch_bounds__(256) void pE_k(FA f) {
  __shared__ __align__(16) char smem[32768];
  u16* As1 = (u16*)smem; u16* As2 = (u16*)(smem + 8192);
  u16* Bs1 = (u16*)(smem + 16384); u16* Bs2 = (u16*)(smem + 24576);
  const int u = blockIdx.x, t = threadIdx.x;
  GA2 d = {};
  d.A1 = f.w_bf; d.A2 = f.W1_bf; d.B1 = f.kT_bf; d.B2 = f.cbT_bf;
  d.lda = 256; d.ldb = 256; d.sAz = 256 * 256; d.sBz = 512 * 256;
  d.Cb = f.s_bf; d.ldc = 512; d.sCz = 256 * 512; d.M = 256; d.K = 256;
  d.e1 = f.ln2g; d.e2 = f.ln2b; d.e3 = f.gam; d.e4 = f.bet; d.e5 = f.S1; d.e6 = f.S2;
  gemm2_core(d, As1, As2, Bs1, Bs2, u % 4, (u / 4) % 8, u / 32, t, 1);
}

// F: attn = s_h @ Wv_h^T (64)
__global__ __launch_bounds__(256) void pF_k(FA f) {
  __shared__ __align__(16) char smem[16384];
  u16* As = (u16*)smem; u16* Bs = (u16*)(smem + 8192);
  const int u = blockIdx.x, t = threadIdx.x;
  GA a = {}; a.A = f.s_bf; a.lda = 4096; a.sAz = 512;
  a.B = f.Wv_bf; a.ldb = 512; a.sBz = 64 * 512;
  a.Cb = f.attn_bf; a.ldc = 512; a.sCz = 64; a.M = 512; a.K = 512; a.epi = 1;
  gemm_core(a, As, Bs, u % 8, 0, u / 8, t);
}

// G: out = attn @ Wfc^T (64)
__global__ __launch_bounds__(256) void pG_k(FA f) {
  __shared__ __align__(16) char smem[16384];
  u16* As = (u16*)smem; u16* Bs = (u16*)(smem + 8192);
  const int u = blockIdx.x, t = threadIdx.x;
  GA a = {}; a.A = f.attn_bf; a.lda = 512;
  a.B = f.Wfc_bf; a.ldb = 512;
  a.Cf = f.out; a.ldc = 512; a.M = 512; a.K = 512; a.epi = 0;
  gemm_core(a, As, Bs, u % 8, u / 8, 0, t);
}

}  // namespace

extern "C" void kernel_launch(void* const* d_in, const int* in_sizes, int n_in,
                              void* d_out, int out_size, void* d_ws, size_t ws_size,
                              hipStream_t stream) {
  (void)in_sizes; (void)n_in; (void)out_size;
  FA fa;
  fa.q    = (const float*)d_in[0];
  fa.k    = (const float*)d_in[1];
  fa.Wq   = (const float*)d_in[3];
  fa.Wk   = (const float*)d_in[4];
  fa.Wv   = (const float*)d_in[5];
  fa.Wfc  = (const float*)d_in[6];
  fa.Wg   = (const float*)d_in[7];
  fa.bg   = (const float*)d_in[8];
  fa.Wvp  = (const float*)d_in[9];
  fa.bvp  = (const float*)d_in[10];
  fa.ln1g = (const float*)d_in[11];
  fa.ln1b = (const float*)d_in[12];
  fa.ln2g = (const float*)d_in[13];
  fa.ln2b = (const float*)d_in[14];
  fa.out  = (float*)d_out;

  // ---- workspace layout (bump allocator; identical sequence to rounds 3-6,
  //      proven to fit; some slots now unused but kept for layout parity) ----
  char* base = (char*)d_ws;
  size_t off = 0;
  auto au16 = [&](size_t n) -> u16* {
    u16* p = (u16*)(base + off); off = (off + n * 2 + 255) & ~(size_t)255; return p;
  };
  auto af32 = [&](size_t n) -> float* {
    float* p = (float*)(base + off); off = (off + n * 4 + 255) & ~(size_t)255; return p;
  };
  (void)au16(262144);               // q_bf (unused)
  (void)au16(524288);               // Wg_bf (unused)
  (void)au16(262144);               // Wq_bf (unused)
  (void)au16(262144);               // Wvp_bf (unused)
  fa.WkT_bf  = au16(262144);
  fa.Wv_bf   = au16(262144);
  fa.Wfc_bf  = au16(262144);
  fa.k_bf    = au16(2097152);
  fa.kT_bf   = au16(2097152);
  fa.qh_bf   = au16(262144);
  fa.gam     = af32(262144);
  fa.bet     = af32(262144);
  fa.condpre = af32(2097152);       // K1 = first half, K2 = second half (post-LN)
  fa.cb_bf   = au16(2097152);
  fa.cbT_bf  = au16(2097152);
  fa.u_bf    = au16(2097152);
  fa.w1_bf   = au16(2097152);
  fa.c2      = af32(4096);
  fa.c3      = af32(4096);
  fa.c4      = af32(4096);
  fa.A96_bf  = au16(16 * 96 * 512);
  fa.sum_be  = af32(512);
  fa.sum_be2 = af32(512);
  fa.P       = af32(16 * 96 * 256);
  float* sbuf   = af32(1048576);
  float* logits = af32(1048576);    // holds cb^2 (bf16) from LN until done
  fa.w_bf    = au16(1048576);
  fa.W1_bf   = au16(1048576);
  fa.S1      = af32(4096);
  fa.S2      = af32(4096);
  fa.attn_bf = au16(262144);
  const size_t need = off;
  fa.s_bf    = (u16*)sbuf;
  fa.cbsq_bf = (u16*)logits;
  fa.K1      = fa.condpre;          // condpre dead after LN (phase B)
  fa.K2      = fa.condpre + 1048576;

  if (ws_size < need) return;  // fail loudly via validation

  const dim3 blk(256);
  pA_k<<<dim3(2560), blk, 0, stream>>>(fa);
  pB_k<<<dim3(1664), blk, 0, stream>>>(fa);
  pC_k<<<dim3(1920), blk, 0, stream>>>(fa);
  pD_k<<<dim3(1024), blk, 0, stream>>>(fa);
  pE_k<<<dim3(512),  blk, 0, stream>>>(fa);
  pF_k<<<dim3(64),   blk, 0, stream>>>(fa);
  pG_k<<<dim3(64),   blk, 0, stream>>>(fa);
}